// Round 13
// baseline (1332.186 us; speedup 1.0000x reference)
//
#include <hip/hip_runtime.h>
#include <hip/hip_bf16.h>
#include <cstdint>
#include <cstddef>

#define N_G 50000
#define N_D 20000
#define E_G 300000
#define E_D 150000
#define BATCH 65536

typedef _Float16 f16;
typedef _Float16 f16x8 __attribute__((ext_vector_type(8)));
typedef _Float16 f16x4 __attribute__((ext_vector_type(4)));
typedef float f32x4 __attribute__((ext_vector_type(4)));

__device__ __forceinline__ float clampf(float v) {
    return fminf(fmaxf(v, -60000.f), 60000.f);  // also squashes NaN
}

__device__ __forceinline__ void gl_lds16(const void* g, void* l) {
    __builtin_amdgcn_global_load_lds(
        (const __attribute__((address_space(1))) unsigned int*)g,
        (__attribute__((address_space(3))) unsigned int*)l, 16, 0, 0);
}

// ---------------- GEMM (128x128, 4 waves): C = act(A @ Bt^T + bias) ----------------
// Pure 84-VGPR form (R15-verified; R17 A/B: wins lin2). lin2 / lin3(+lin4).
__global__ __launch_bounds__(256) void gemm_f16(
    const f16* __restrict__ A,
    const int* __restrict__ bidx,
    const f16* __restrict__ geneT, const f16* __restrict__ disT, int rowBase,
    const f16* __restrict__ Bt, const float* __restrict__ bias,
    f16* __restrict__ C, int M, int N, int K, int relu, int CB, int RB,
    const float* __restrict__ W4, float* __restrict__ outF)
{
    alignas(16) __shared__ f16 sA[128 * 64];
    alignas(16) __shared__ f16 sB[128 * 64];
    const int t = threadIdx.x;
    const int w = t >> 6, l = t & 63;
    const int wm = w >> 1, wn = w & 1;
    const int q = l >> 4, lr = l & 15;

    int flat = blockIdx.x;
    int cb, rb;
    if ((RB & 7) == 0) {
        int x = flat & 7, idx = flat >> 3;
        int Sx = RB >> 3;
        cb = idx % CB;
        rb = x * Sx + idx / CB;
    } else {
        cb = flat % CB;
        rb = flat / CB;
    }
    const int mBase = rb * 128, nBase = cb * 128;

    const int subrow = l >> 3;   // 0..7
    const int c = l & 7;         // 16B chunk 0..7 within a 128B row
    const char* pA[4];
    const char* pD[4];
    const char* pB[4];
    const bool fused = (bidx != nullptr);
    const bool concat = (!fused && disT != nullptr);
    const bool twoSrc = fused || concat;
#pragma unroll
    for (int j = 0; j < 4; j++) {
        int seg = j * 4 + w;
        int lrow = seg * 8 + subrow;               // 0..127
        int coff = ((c ^ (lrow & 7)) << 4);        // swizzled chunk byte offset
        if (fused) {
            int rg = rowBase + mBase + lrow;       // M % 128 == 0 on this path
            int gi = bidx[2 * rg], di = bidx[2 * rg + 1];
            pA[j] = (const char*)geneT + (size_t)gi * 512 + coff;
            pD[j] = (const char*)disT + (size_t)di * 512 + coff;
        } else if (concat) {
            int arow = mBase + lrow; if (arow > M - 1) arow = M - 1;
            pA[j] = (const char*)geneT + (size_t)arow * 512 + coff;
            pD[j] = (const char*)disT + (size_t)arow * 512 + coff;
        } else {
            int arow = mBase + lrow; if (arow > M - 1) arow = M - 1;
            pA[j] = (const char*)A + (size_t)arow * K * 2 + coff;
            pD[j] = nullptr;
        }
        int brow = nBase + lrow; if (brow > N - 1) brow = N - 1;
        pB[j] = (const char*)Bt + (size_t)brow * K * 2 + coff;
    }

    f32x4 acc[4][4] = {};

    for (int k0 = 0; k0 < K; k0 += 64) {
        __syncthreads();
#pragma unroll
        for (int j = 0; j < 4; j++) {
            int seg = j * 4 + w;
            const char* srcA;
            if (twoSrc)
                srcA = (k0 < 256) ? (pA[j] + (size_t)k0 * 2) : (pD[j] + (size_t)(k0 - 256) * 2);
            else
                srcA = pA[j] + (size_t)k0 * 2;
            gl_lds16(srcA, sA + seg * 512);
            gl_lds16(pB[j] + (size_t)k0 * 2, sB + seg * 512);
        }
        __syncthreads();
        f16x8 a0[4], a1[4], b0[4], b1[4];
#pragma unroll
        for (int i = 0; i < 4; i++) {
            int r = wm * 64 + i * 16 + lr;
            int rs = r * 64;
            int x0 = (q ^ (r & 7)) << 3;
            int x1 = ((4 + q) ^ (r & 7)) << 3;
            a0[i] = *(const f16x8*)(sA + rs + x0);
            a1[i] = *(const f16x8*)(sA + rs + x1);
        }
#pragma unroll
        for (int jj = 0; jj < 4; jj++) {
            int r = wn * 64 + jj * 16 + lr;
            int rs = r * 64;
            int x0 = (q ^ (r & 7)) << 3;
            int x1 = ((4 + q) ^ (r & 7)) << 3;
            b0[jj] = *(const f16x8*)(sB + rs + x0);
            b1[jj] = *(const f16x8*)(sB + rs + x1);
        }
#pragma unroll
        for (int i = 0; i < 4; i++)
#pragma unroll
            for (int jj = 0; jj < 4; jj++) {
                acc[i][jj] = __builtin_amdgcn_mfma_f32_16x16x32_f16(a0[i], b0[jj], acc[i][jj], 0, 0, 0);
                acc[i][jj] = __builtin_amdgcn_mfma_f32_16x16x32_f16(a1[i], b1[jj], acc[i][jj], 0, 0, 0);
            }
    }

    if (W4 != nullptr) {
        // fused final linear: out[rowBase+row] += lrelu(acc + bias) @ W4 (512x2)
        float w40[4], w41[4];
#pragma unroll
        for (int j = 0; j < 4; j++) {
            int col = nBase + wn * 64 + j * 16 + lr;
            w40[j] = W4[col * 2];
            w41[j] = W4[col * 2 + 1];
        }
#pragma unroll
        for (int i = 0; i < 4; i++) {
#pragma unroll
            for (int r = 0; r < 4; r++) {
                int row = mBase + wm * 64 + i * 16 + q * 4 + r;
                float s0 = 0.f, s1 = 0.f;
#pragma unroll
                for (int j = 0; j < 4; j++) {
                    int col = nBase + wn * 64 + j * 16 + lr;
                    float v = acc[i][j][r] + bias[col];
                    v = v >= 0.f ? v : 0.01f * v;
                    v = clampf(v);
                    s0 += v * w40[j];
                    s1 += v * w41[j];
                }
#pragma unroll
                for (int off = 1; off < 16; off <<= 1) {
                    s0 += __shfl_xor(s0, off);
                    s1 += __shfl_xor(s1, off);
                }
                if (lr == 0 && row < M) {
                    atomicAdd(&outF[(size_t)(rowBase + row) * 2], s0);
                    atomicAdd(&outF[(size_t)(rowBase + row) * 2 + 1], s1);
                }
            }
        }
        return;
    }

    // ---- epilogue: per-wave LDS transpose, then coalesced f16x8 stores ----
    __syncthreads();
    f16* lt = ((w >> 1) ? sB : sA) + (w & 1) * 4096;

    float bj[4];
#pragma unroll
    for (int j = 0; j < 4; j++)
        bj[j] = bias ? bias[nBase + wn * 64 + j * 16 + lr] : 0.f;

#pragma unroll
    for (int i = 0; i < 4; i++)
#pragma unroll
        for (int j = 0; j < 4; j++) {
            int col = j * 16 + lr;
#pragma unroll
            for (int r = 0; r < 4; r++) {
                int row = i * 16 + q * 4 + r;       // 0..63 wave-local
                float v = acc[i][j][r] + bj[j];
                if (relu) v = v >= 0.f ? v : 0.01f * v;
                v = clampf(v);
                int cs = col ^ ((((row >> 2) & 3) << 4) ^ ((row & 3) << 3));
                lt[row * 64 + cs] = (f16)v;
            }
        }
    __syncthreads();

    const int rr = l >> 3;
    const int c8 = l & 7;
#pragma unroll
    for (int it = 0; it < 8; it++) {
        int row = it * 8 + rr;
        int cs = (c8 * 8) ^ ((((row >> 2) & 3) << 4) ^ ((row & 3) << 3));
        f16x8 vv = *(const f16x8*)(lt + row * 64 + cs);
        int grow = mBase + wm * 64 + row;
        if (grow < M)
            *(f16x8*)(C + (size_t)grow * N + nBase + wn * 64 + c8 * 8) = vv;
    }
}

// ---------------- R20: gemm_wide (128x512 tile, 8 waves) for lin1 gather ------------
// Theory: lin1 at CB=8 refetches every gathered pair-row 8x through LLC (~1 GB).
// Wide-N tile (CB=4) halves A-refetch; B (W1T, 2MB) is L2-resident and cheap.
// Structure: proven single-buffer 2-barrier loop, 2 blocks/CU (80 KB LDS).
// Wave w: output rows 0..127 x cols w*64..w*64+63 (acc[8][4], gemm256 fragment math).
// Epilogue: R12-verified two-pass 64-row transpose (8 KB slice/wave).
__global__ __launch_bounds__(512) void gemm_wide(
    const int* __restrict__ bidx,
    const f16* __restrict__ geneT, const f16* __restrict__ disT, int rowBase,
    const f16* __restrict__ Bt, const float* __restrict__ bias,
    f16* __restrict__ C, int M, int N, int K, int CB, int RB)
{
    alignas(16) __shared__ f16 sm[40960];   // sA 128x64 | sB 512x64  (80 KB)
    f16* const sA = sm;
    f16* const sB = sm + 8192;
    const int t = threadIdx.x;
    const int w = t >> 6, l = t & 63;
    const int q = l >> 4, lr = l & 15;
    const int subrow = l >> 3, c = l & 7;

    int flat = blockIdx.x;
    int cb, rb;
    if ((RB & 7) == 0) {
        int x = flat & 7, idx = flat >> 3;
        int Sx = RB >> 3;
        cb = idx % CB;
        rb = x * Sx + idx / CB;
    } else {
        cb = flat % CB;
        rb = flat / CB;
    }
    const int mBase = rb * 128, nBase = cb * 512;

    // A gather pointers: 2 staging issues per thread, rows (w*2+j)*8+subrow (0..127)
    const char* pA[2];
    const char* pD[2];
#pragma unroll
    for (int j = 0; j < 2; j++) {
        int row = (w * 2 + j) * 8 + subrow;
        int coff = ((c ^ (row & 7)) << 4);
        int rg = rowBase + mBase + row;            // M % 128 == 0
        int gi = bidx[2 * rg], di = bidx[2 * rg + 1];
        pA[j] = (const char*)geneT + (size_t)gi * 512 + coff;
        pD[j] = (const char*)disT + (size_t)di * 512 + coff;
    }
    // B pointers: 8 issues per thread, rows (jj*8+w)*8+subrow (0..511)
    const char* pB[8];
#pragma unroll
    for (int jj = 0; jj < 8; jj++) {
        int row = (jj * 8 + w) * 8 + subrow;
        int coff = ((c ^ (row & 7)) << 4);
        int brow = nBase + row; if (brow > N - 1) brow = N - 1;
        pB[jj] = (const char*)Bt + (size_t)brow * K * 2 + coff;
    }

    f32x4 acc[8][4] = {};

    for (int k0 = 0; k0 < K; k0 += 64) {
        __syncthreads();
#pragma unroll
        for (int j = 0; j < 2; j++) {
            const char* srcA = (k0 < 256) ? (pA[j] + (size_t)k0 * 2)
                                          : (pD[j] + (size_t)(k0 - 256) * 2);
            gl_lds16(srcA, sA + (w * 2 + j) * 512);
        }
#pragma unroll
        for (int jj = 0; jj < 8; jj++)
            gl_lds16(pB[jj] + (size_t)k0 * 2, sB + (jj * 8 + w) * 512);
        __syncthreads();
#pragma unroll
        for (int ks = 0; ks < 2; ks++) {
            f16x8 bf[4];
#pragma unroll
            for (int nf = 0; nf < 4; nf++) {
                int rB = w * 64 + nf * 16 + lr;
                bf[nf] = *(const f16x8*)(sB + rB * 64 + ((((ks << 2) + q) ^ (rB & 7)) << 3));
            }
#pragma unroll
            for (int mf = 0; mf < 8; mf++) {
                int rA = mf * 16 + lr;
                f16x8 af = *(const f16x8*)(sA + rA * 64 + ((((ks << 2) + q) ^ (rA & 7)) << 3));
#pragma unroll
                for (int nf = 0; nf < 4; nf++)
                    acc[mf][nf] = __builtin_amdgcn_mfma_f32_16x16x32_f16(af, bf[nf], acc[mf][nf], 0, 0, 0);
            }
        }
    }

    // ---- epilogue: two passes of 64 rows, 8 KB slice per wave, f16x8 stores ----
    f16* lt = sm + w * 4096;
    float bj[4];
#pragma unroll
    for (int nf = 0; nf < 4; nf++)
        bj[nf] = bias[nBase + w * 64 + nf * 16 + lr];

    const int rr = l >> 3;
    const int c8 = l & 7;
#pragma unroll
    for (int half = 0; half < 2; half++) {
        __syncthreads();   // all waves done with prior LDS contents
#pragma unroll
        for (int mh = 0; mh < 4; mh++) {
            int mf = half * 4 + mh;
#pragma unroll
            for (int nf = 0; nf < 4; nf++) {
                int col = nf * 16 + lr;
#pragma unroll
                for (int r = 0; r < 4; r++) {
                    int row = mh * 16 + q * 4 + r;  // 0..63 within this half
                    float v = acc[mf][nf][r] + bj[nf];
                    v = v >= 0.f ? v : 0.01f * v;   // lin1 always lrelu
                    v = clampf(v);
                    int cs = col ^ ((((row >> 2) & 3) << 4) ^ ((row & 3) << 3));
                    lt[row * 64 + cs] = (f16)v;
                }
            }
        }
        __syncthreads();   // writes visible
#pragma unroll
        for (int it = 0; it < 8; it++) {
            int row = it * 8 + rr;                  // 0..63 within this half
            int cs = (c8 * 8) ^ ((((row >> 2) & 3) << 4) ^ ((row & 3) << 3));
            f16x8 vv = *(const f16x8*)(lt + row * 64 + cs);
            int grow = mBase + half * 64 + row;
            if (grow < M)
                *(f16x8*)(C + (size_t)grow * N + nBase + w * 64 + c8 * 8) = vv;
        }
    }
}

// ---------------- merged tower GEMM: gene blocks then disease blocks ----------------
// y = lrelu([X|XA] @ Bt^T + bias); fused column stats. N=256, K=512, CB=2 hardwired.
__global__ __launch_bounds__(256) void gemm_tower2(
    const f16* __restrict__ Xg, const f16* __restrict__ XAg,
    const f16* __restrict__ Btg, const float* __restrict__ biasg,
    f16* __restrict__ Cg, int Mg, int RBg, float* __restrict__ statsg,
    const f16* __restrict__ Xd, const f16* __restrict__ XAd,
    const f16* __restrict__ Btd, const float* __restrict__ biasd,
    f16* __restrict__ Cd, int Md, int RBd, float* __restrict__ statsd)
{
    alignas(16) __shared__ f16 sA[128 * 64];
    alignas(16) __shared__ f16 sB[128 * 64];
    const int t = threadIdx.x;
    const int w = t >> 6, l = t & 63;
    const int wm = w >> 1, wn = w & 1;
    const int q = l >> 4, lr = l & 15;

    // tower select by block range
    int flat = blockIdx.x;
    const int geneBlocks = 2 * RBg;
    const f16* X;  const f16* XA;  const f16* Bt;  const float* bias;
    f16* C;  int M, RB;  float* stats;
    if (flat < geneBlocks) {
        X = Xg; XA = XAg; Bt = Btg; bias = biasg; C = Cg; M = Mg; RB = RBg; stats = statsg;
    } else {
        flat -= geneBlocks;
        X = Xd; XA = XAd; Bt = Btd; bias = biasd; C = Cd; M = Md; RB = RBd; stats = statsd;
    }

    int cb, rb;
    if ((RB & 7) == 0) {
        int x = flat & 7, idx = flat >> 3;
        int Sx = RB >> 3;
        cb = idx % 2;
        rb = x * Sx + idx / 2;
    } else {
        cb = flat % 2;
        rb = flat / 2;
    }
    const int mBase = rb * 128, nBase = cb * 128;

    const int subrow = l >> 3;
    const int c = l & 7;
    const char* pA[4];
    const char* pD[4];
    const char* pB[4];
#pragma unroll
    for (int j = 0; j < 4; j++) {
        int seg = j * 4 + w;
        int lrow = seg * 8 + subrow;
        int coff = ((c ^ (lrow & 7)) << 4);
        int arow = mBase + lrow; if (arow > M - 1) arow = M - 1;
        pA[j] = (const char*)X + (size_t)arow * 512 + coff;
        pD[j] = (const char*)XA + (size_t)arow * 512 + coff;
        int brow = nBase + lrow; if (brow > 255) brow = 255;
        pB[j] = (const char*)Bt + (size_t)brow * 1024 + coff;
    }

    f32x4 acc[4][4] = {};

    for (int k0 = 0; k0 < 512; k0 += 64) {
        __syncthreads();
#pragma unroll
        for (int j = 0; j < 4; j++) {
            int seg = j * 4 + w;
            const char* srcA = (k0 < 256) ? (pA[j] + (size_t)k0 * 2)
                                          : (pD[j] + (size_t)(k0 - 256) * 2);
            gl_lds16(srcA, sA + seg * 512);
            gl_lds16(pB[j] + (size_t)k0 * 2, sB + seg * 512);
        }
        __syncthreads();
        f16x8 a0[4], a1[4], b0[4], b1[4];
#pragma unroll
        for (int i = 0; i < 4; i++) {
            int r = wm * 64 + i * 16 + lr;
            int rs = r * 64;
            int x0 = (q ^ (r & 7)) << 3;
            int x1 = ((4 + q) ^ (r & 7)) << 3;
            a0[i] = *(const f16x8*)(sA + rs + x0);
            a1[i] = *(const f16x8*)(sA + rs + x1);
        }
#pragma unroll
        for (int jj = 0; jj < 4; jj++) {
            int r = wn * 64 + jj * 16 + lr;
            int rs = r * 64;
            int x0 = (q ^ (r & 7)) << 3;
            int x1 = ((4 + q) ^ (r & 7)) << 3;
            b0[jj] = *(const f16x8*)(sB + rs + x0);
            b1[jj] = *(const f16x8*)(sB + rs + x1);
        }
#pragma unroll
        for (int i = 0; i < 4; i++)
#pragma unroll
            for (int jj = 0; jj < 4; jj++) {
                acc[i][jj] = __builtin_amdgcn_mfma_f32_16x16x32_f16(a0[i], b0[jj], acc[i][jj], 0, 0, 0);
                acc[i][jj] = __builtin_amdgcn_mfma_f32_16x16x32_f16(a1[i], b1[jj], acc[i][jj], 0, 0, 0);
            }
    }

    // ---- epilogue: bias, lrelu, fused stats, LDS transpose, store ----
    __syncthreads();
    f16* lt = ((w >> 1) ? sB : sA) + (w & 1) * 4096;

    float bj[4];
#pragma unroll
    for (int j = 0; j < 4; j++)
        bj[j] = bias[nBase + wn * 64 + j * 16 + lr];

    float sj[4] = {0.f, 0.f, 0.f, 0.f}, s2j[4] = {0.f, 0.f, 0.f, 0.f};
#pragma unroll
    for (int i = 0; i < 4; i++)
#pragma unroll
        for (int j = 0; j < 4; j++) {
            int col = j * 16 + lr;
#pragma unroll
            for (int r = 0; r < 4; r++) {
                int row = i * 16 + q * 4 + r;
                float v = acc[i][j][r] + bj[j];
                v = v >= 0.f ? v : 0.01f * v;
                v = clampf(v);
                if ((mBase + wm * 64 + row) < M) { sj[j] += v; s2j[j] += v * v; }
                int cs = col ^ ((((row >> 2) & 3) << 4) ^ ((row & 3) << 3));
                lt[row * 64 + cs] = (f16)v;
            }
        }

#pragma unroll
    for (int j = 0; j < 4; j++) {
        float s = sj[j], s2 = s2j[j];
        s += __shfl_xor(s, 16); s2 += __shfl_xor(s2, 16);
        s += __shfl_xor(s, 32); s2 += __shfl_xor(s2, 32);
        if (q == 0) {
            int col = nBase + wn * 64 + j * 16 + lr;
            atomicAdd(&stats[col], s);
            atomicAdd(&stats[256 + col], s2);
        }
    }
    __syncthreads();

    const int rr = l >> 3;
    const int c8 = l & 7;
#pragma unroll
    for (int it = 0; it < 8; it++) {
        int row = it * 8 + rr;
        int cs = (c8 * 8) ^ ((((row >> 2) & 3) << 4) ^ ((row & 3) << 3));
        f16x8 vv = *(const f16x8*)(lt + row * 64 + cs);
        int grow = mBase + wm * 64 + row;
        if (grow < M)
            *(f16x8*)(C + (size_t)grow * 256 + nBase + wn * 64 + c8 * 8) = vv;
    }
}

// ---------------- merged small kernels ----------------
__global__ void cvt2(const float* __restrict__ gx, const float* __restrict__ dx,
                     f16* __restrict__ og, f16* __restrict__ od) {
    size_t i = ((size_t)blockIdx.x * 256 + threadIdx.x) * 8;
    const size_t ng = (size_t)N_G * 256;
    const float* in; f16* out;
    if (i < ng) { in = gx + i; out = og + i; }
    else {
        size_t j = i - ng;
        if (j >= (size_t)N_D * 256) return;
        in = dx + j; out = od + j;
    }
    f32x4 a = *(const f32x4*)in;
    f32x4 b = *(const f32x4*)(in + 4);
    f16x8 o;
    o[0] = (f16)clampf(a.x); o[1] = (f16)clampf(a.y);
    o[2] = (f16)clampf(a.z); o[3] = (f16)clampf(a.w);
    o[4] = (f16)clampf(b.x); o[5] = (f16)clampf(b.y);
    o[6] = (f16)clampf(b.z); o[7] = (f16)clampf(b.w);
    *(f16x8*)out = o;
}

__global__ void init_out(const float* __restrict__ b4, float* __restrict__ out, int n) {
    int i = blockIdx.x * 256 + threadIdx.x;
    if (i < n) out[i] = b4[i & 1];
}

__global__ void count_deg2(const int* __restrict__ gei, const int* __restrict__ dei,
                           int* __restrict__ cntg, int* __restrict__ cntd) {
    int e = blockIdx.x * 256 + threadIdx.x;
    if (e < E_G) atomicAdd(&cntg[gei[E_G + e]], 1);
    else if (e < E_G + E_D) atomicAdd(&cntd[dei[E_D + (e - E_G)]], 1);
}

__global__ void scan_deg2(const int* __restrict__ cntg, int* __restrict__ rpg,
                          const int* __restrict__ cntd, int* __restrict__ rpd) {
    __shared__ int part[1024];
    const int t = threadIdx.x;
    const int* deg = blockIdx.x ? cntd : cntg;
    int* rowptr = blockIdx.x ? rpd : rpg;
    const int Nn = blockIdx.x ? N_D : N_G;
    const int C = (Nn + 1023) >> 10;
    const int base = t * C;
    int s = 0;
    for (int i = 0; i < C; i++) { int idx = base + i; if (idx < Nn) s += deg[idx]; }
    part[t] = s;
    __syncthreads();
    for (int off = 1; off < 1024; off <<= 1) {
        int v = (t >= off) ? part[t - off] : 0;
        __syncthreads();
        part[t] += v;
        __syncthreads();
    }
    int pre = (t == 0) ? 0 : part[t - 1];
    for (int i = 0; i < C; i++) {
        int idx = base + i;
        if (idx < Nn) { rowptr[idx] = pre; pre += deg[idx]; }
    }
    if (t == 1023) rowptr[Nn] = part[1023];
}

__global__ void fill_csr2(const int* __restrict__ gei, const int* __restrict__ dei,
                          const int* __restrict__ rpg, const int* __restrict__ rpd,
                          int* __restrict__ curg, int* __restrict__ curd,
                          int* __restrict__ csrg, int* __restrict__ csrd) {
    int e = blockIdx.x * 256 + threadIdx.x;
    if (e < E_G) {
        int d = gei[E_G + e];
        int p = rpg[d] + atomicAdd(&curg[d], 1);
        csrg[p] = gei[e];
    } else if (e < E_G + E_D) {
        int e2 = e - E_G;
        int d = dei[E_D + e2];
        int p = rpd[d] + atomicAdd(&curd[d], 1);
        csrd[p] = dei[e2];
    }
}

// merged pre-aggregation: XA[i] = sum_{j->i} X[j] for both towers
__global__ void agg_x2(const int* __restrict__ rpg, const int* __restrict__ csrg,
                       const f16* __restrict__ Xg, f16* __restrict__ XAg,
                       const int* __restrict__ rpd, const int* __restrict__ csrd,
                       const f16* __restrict__ Xd, f16* __restrict__ XAd) {
    int gid = blockIdx.x * 256 + threadIdx.x;
    int node = gid >> 6, l = gid & 63;
    const int* rowptr; const int* csr; const f16* X; f16* XA;
    if (node < N_G) { rowptr = rpg; csr = csrg; X = Xg; XA = XAg; }
    else {
        node -= N_G;
        if (node >= N_D) return;
        rowptr = rpd; csr = csrd; X = Xd; XA = XAd;
    }
    int beg = rowptr[node], end = rowptr[node + 1];
    float s0 = 0.f, s1 = 0.f, s2 = 0.f, s3 = 0.f;
    for (int e = beg; e < end; e++) {
        int src = csr[e];
        f16x4 xv = *(const f16x4*)(X + (size_t)src * 256 + l * 4);
        s0 += (float)xv.x; s1 += (float)xv.y; s2 += (float)xv.z; s3 += (float)xv.w;
    }
    f16x4 o;
    o.x = (f16)clampf(s0); o.y = (f16)clampf(s1);
    o.z = (f16)clampf(s2); o.w = (f16)clampf(s3);
    *(f16x4*)(XA + (size_t)node * 256 + l * 4) = o;
}

// merged BN: y = BN(y); acc = (initAcc?0:acc) + w*BN(y), for both towers.
__global__ void bn_apply2(f16* __restrict__ yg, f16* __restrict__ yd,
                          const float* __restrict__ stg, const float* __restrict__ std_,
                          const float* __restrict__ gg, const float* __restrict__ bg,
                          const float* __restrict__ gd, const float* __restrict__ bd,
                          float invNg, float invNd, float wv,
                          f16* __restrict__ accg, f16* __restrict__ accd, int initAcc) {
    size_t i = ((size_t)blockIdx.x * 256 + threadIdx.x) * 8;
    const size_t ng = (size_t)N_G * 256;
    f16* y; f16* acc; const float* stats; const float* g; const float* b; float invN;
    if (i < ng) { y = yg + i; acc = accg + i; stats = stg; g = gg; b = bg; invN = invNg; }
    else {
        size_t j = i - ng;
        if (j >= (size_t)N_D * 256) return;
        y = yd + j; acc = accd + j; stats = std_; g = gd; b = bd; invN = invNd;
    }
    int colb = (int)(i & 255);
    f16x8 yv = *(const f16x8*)y;
    f16x8 av = {};
    if (!initAcc) av = *(const f16x8*)acc;
    f16x8 yo, ao;
#pragma unroll
    for (int j = 0; j < 8; j++) {
        int col = colb + j;
        float m = stats[col] * invN;
        float var = stats[256 + col] * invN - m * m;
        if (var < 0.f) var = 0.f;
        float rs = 1.0f / sqrtf(var + 1e-5f);
        float v = ((float)yv[j] - m) * rs * g[col] + b[col];
        v = clampf(v);
        yo[j] = (f16)v;
        float p = initAcc ? 0.f : (float)av[j];
        ao[j] = (f16)clampf(p + wv * v);
    }
    *(f16x8*)y = yo;
    *(f16x8*)acc = ao;
}

// Tiled transpose: WT[(dstRowOff+n)*LK + dstColOff + k] = W[k][n]  (head weights)
__global__ void transpose_tile(const float* __restrict__ W, f16* __restrict__ WT,
                               int K, int N, int dstRowOff, int dstColOff, int LK) {
    __shared__ float tile[32][33];
    int n0 = blockIdx.x * 32, k0 = blockIdx.y * 32;
    int tx = threadIdx.x, ty = threadIdx.y;
    for (int yy = ty; yy < 32; yy += 8) {
        int k = k0 + yy, n = n0 + tx;
        tile[yy][tx] = (k < K && n < N) ? W[(size_t)k * N + n] : 0.f;
    }
    __syncthreads();
    for (int yy = ty; yy < 32; yy += 8) {
        int n = n0 + yy, k = k0 + tx;
        if (n < N && k < K)
            WT[(size_t)(dstRowOff + n) * LK + dstColOff + k] = (f16)clampf(tile[tx][yy]);
    }
}

// ALL 12 tower weight-panel transposes (6 layers x Ws/Wr) in one launch.
struct WPtrs { const float* p[12]; };
__global__ void transpose12(WPtrs wp, f16* __restrict__ WT) {
    __shared__ float tile[32][33];
    const int z = blockIdx.z;
    const float* W = wp.p[z];
    const int s = z >> 1;
    const int colOff = (z & 1) * 256;
    f16* dst = WT + (size_t)s * 131072;
    int n0 = blockIdx.x * 32, k0 = blockIdx.y * 32;
    int tx = threadIdx.x, ty = threadIdx.y;
    for (int yy = ty; yy < 32; yy += 8)
        tile[yy][tx] = W[(size_t)(k0 + yy) * 256 + n0 + tx];
    __syncthreads();
    for (int yy = ty; yy < 32; yy += 8)
        dst[(size_t)(n0 + yy) * 512 + colOff + k0 + tx] = (f16)clampf(tile[tx][yy]);
}

extern "C" void kernel_launch(void* const* d_in, const int* in_sizes, int n_in,
                              void* d_out, int out_size, void* d_ws, size_t ws_size,
                              hipStream_t stream) {
    char* ws = (char*)d_ws;
    size_t off = 0;
    auto alloc = [&](size_t bytes) -> void* {
        void* p = ws + off;
        off += (bytes + 255) & ~(size_t)255;
        return p;
    };

    // persistent
    f16* gene_out = (f16*)alloc((size_t)N_G * 256 * 2);
    f16* dis_out  = (f16*)alloc((size_t)N_D * 256 * 2);
    f16* W1T = (f16*)alloc((size_t)2048 * 512 * 2);
    f16* W2T = (f16*)alloc((size_t)1024 * 2048 * 2);
    f16* W3T = (f16*)alloc((size_t)512 * 1024 * 2);
    f16* WcatT = (f16*)alloc((size_t)6 * 256 * 512 * 2);   // 6 slices (gene l0-2, dis l0-2)
    int* csr_g = (int*)alloc((size_t)E_G * 4);
    int* csr_d = (int*)alloc((size_t)E_D * 4);
    int* rp_g = (int*)alloc((size_t)(N_G + 1) * 4);
    int* rp_d = (int*)alloc((size_t)(N_D + 1) * 4);
    int* cnt = (int*)alloc((size_t)(N_G + N_D) * 4);       // cnt_g | cnt_d contiguous
    int* cnt_g = cnt;
    int* cnt_d = cnt + N_G;
    float* statsAll = (float*)alloc(6 * 512 * 4);          // gene l0-2, dis l0-2

    char* scratch = ws + off;
    size_t avail = (ws_size > off) ? (ws_size - off) : 0;

    // tower buffers: gene ping/pong/XA then disease ping/pong/XA (~108 MB)
    const size_t NSG = (size_t)N_G * 256;
    const size_t NSD = (size_t)N_D * 256;
    f16* gX = (f16*)scratch;
    f16* gY = gX + NSG;
    f16* gXA = gY + NSG;
    f16* dX = gXA + NSG;
    f16* dY = dX + NSD;
    f16* dXA = dY + NSD;

    // head chunk (aliases scratch after towers): R rows use R*6144 bytes
    int R = BATCH;
    while ((size_t)R * 6144 > avail && R > 256) R >>= 1;
    int chunks = BATCH / R;
    f16* h1 = (f16*)scratch;
    f16* h2 = h1 + (size_t)R * 2048;

    const float* gene_x = (const float*)d_in[0];
    const float* disease_x = (const float*)d_in[1];
    const int* g_ei = (const int*)d_in[2];
    const int* d_ei = (const int*)d_in[3];
    const int* bidx = (const int*)d_in[4];
    float* out = (float*)d_out;

    const float wl[3] = {0.7f, 0.2f, 0.1f};

    // ---- tower setup (merged) ----
    hipMemsetAsync(statsAll, 0, 6 * 512 * 4, stream);
    hipMemsetAsync(cnt, 0, (size_t)(N_G + N_D) * 4, stream);
    {
        size_t tot8 = ((NSG + NSD) / 8 + 255) / 256;
        cvt2<<<(int)tot8, 256, 0, stream>>>(gene_x, disease_x, gX, dX);
    }
    count_deg2<<<(E_G + E_D + 255) / 256, 256, 0, stream>>>(g_ei, d_ei, cnt_g, cnt_d);
    scan_deg2<<<2, 1024, 0, stream>>>(cnt_g, rp_g, cnt_d, rp_d);
    hipMemsetAsync(cnt, 0, (size_t)(N_G + N_D) * 4, stream);
    fill_csr2<<<(E_G + E_D + 255) / 256, 256, 0, stream>>>(g_ei, d_ei, rp_g, rp_d,
                                                           cnt_g, cnt_d, csr_g, csr_d);
    {
        WPtrs wp;
        for (int l = 0; l < 3; l++) {
            wp.p[l * 2 + 0] = (const float*)d_in[5 + l * 5 + 2];   // gene Ws
            wp.p[l * 2 + 1] = (const float*)d_in[5 + l * 5 + 0];   // gene Wr
            wp.p[6 + l * 2 + 0] = (const float*)d_in[20 + l * 5 + 2]; // dis Ws
            wp.p[6 + l * 2 + 1] = (const float*)d_in[20 + l * 5 + 0]; // dis Wr
        }
        transpose12<<<dim3(8, 8, 12), dim3(32, 8), 0, stream>>>(wp, WcatT);
    }

    // ---- tower layers (merged: 3 dispatches per layer) ----
    const int RBg = ((N_G + 127) / 128 + 7) & ~7;   // 392
    const int RBd = ((N_D + 127) / 128 + 7) & ~7;   // 160
    f16* gIn = gX; f16* gOut = gY;
    f16* dIn = dX; f16* dOut = dY;
    int aggBlocks = ((N_G + N_D) * 64 + 255) / 256;
    int bnBlocks = (int)(((NSG + NSD) / 8 + 255) / 256);
    for (int l = 0; l < 3; l++) {
        const float* br_g = (const float*)d_in[5 + l * 5 + 1];
        const float* bg_g = (const float*)d_in[5 + l * 5 + 3];
        const float* bb_g = (const float*)d_in[5 + l * 5 + 4];
        const float* br_d = (const float*)d_in[20 + l * 5 + 1];
        const float* bg_d = (const float*)d_in[20 + l * 5 + 3];
        const float* bb_d = (const float*)d_in[20 + l * 5 + 4];
        agg_x2<<<aggBlocks, 256, 0, stream>>>(rp_g, csr_g, gIn, gXA,
                                              rp_d, csr_d, dIn, dXA);
        gemm_tower2<<<2 * RBg + 2 * RBd, 256, 0, stream>>>(
            gIn, gXA, WcatT + (size_t)l * 131072, br_g, gOut, N_G, RBg, statsAll + l * 512,
            dIn, dXA, WcatT + (size_t)(3 + l) * 131072, br_d, dOut, N_D, RBd,
            statsAll + (3 + l) * 512);
        bn_apply2<<<bnBlocks, 256, 0, stream>>>(gOut, dOut,
                                                statsAll + l * 512, statsAll + (3 + l) * 512,
                                                bg_g, bb_g, bg_d, bb_d,
                                                1.0f / N_G, 1.0f / N_D, wl[l],
                                                gene_out, dis_out, l == 0);
        f16* tmp = gIn; gIn = gOut; gOut = tmp;
        tmp = dIn; dIn = dOut; dOut = tmp;
    }

    // ---- head ----
    const float* lin1_W = (const float*)d_in[35];
    const float* lin1_b = (const float*)d_in[36];
    const float* lin2_W = (const float*)d_in[37];
    const float* lin2_b = (const float*)d_in[38];
    const float* lin3_W = (const float*)d_in[39];
    const float* lin3_b = (const float*)d_in[40];
    const float* lin4_W = (const float*)d_in[41];
    const float* lin4_b = (const float*)d_in[42];

    transpose_tile<<<dim3(64, 16), dim3(32, 8), 0, stream>>>(lin1_W, W1T, 512, 2048, 0, 0, 512);
    transpose_tile<<<dim3(32, 64), dim3(32, 8), 0, stream>>>(lin2_W, W2T, 2048, 1024, 0, 0, 2048);
    transpose_tile<<<dim3(16, 32), dim3(32, 8), 0, stream>>>(lin3_W, W3T, 1024, 512, 0, 0, 1024);
    init_out<<<(BATCH * 2 + 255) / 256, 256, 0, stream>>>(lin4_b, out, BATCH * 2);

    // head: lin1 -> gemm_wide (128x512, CB=4, halves A-refetch), lin2/lin3 -> gemm_f16
    for (int c = 0; c < chunks; c++) {
        int rb = c * R;
        int RB = R / 128;
        if ((R & 127) == 0) {
            gemm_wide<<<4 * RB, 512, 0, stream>>>(bidx, gene_out, dis_out, rb,
                                                  W1T, lin1_b, h1, R, 2048, 512, 4, RB);
        } else {
            gemm_f16<<<16 * RB, 256, 0, stream>>>(nullptr, bidx, gene_out, dis_out, rb,
                                                  W1T, lin1_b, h1, R, 2048, 512, 1, 16, RB,
                                                  nullptr, nullptr);
        }
        gemm_f16<<<8 * RB, 256, 0, stream>>>(h1, nullptr, nullptr, nullptr, 0,
                                             W2T, lin2_b, h2, R, 1024, 2048, 1, 8, RB,
                                             nullptr, nullptr);
        // lin3 with fused lin4: atomics into out (fp32)
        gemm_f16<<<4 * RB, 256, 0, stream>>>(h2, nullptr, nullptr, nullptr, rb,
                                             W3T, lin3_b, nullptr, R, 512, 1024, 1, 4, RB,
                                             lin4_W, out);
    }
}

// Round 14
// 1316.694 us; speedup vs baseline: 1.0118x; 1.0118x over previous
//
#include <hip/hip_runtime.h>
#include <hip/hip_bf16.h>
#include <cstdint>
#include <cstddef>

#define N_G 50000
#define N_D 20000
#define E_G 300000
#define E_D 150000
#define BATCH 65536

typedef _Float16 f16;
typedef _Float16 f16x8 __attribute__((ext_vector_type(8)));
typedef _Float16 f16x4 __attribute__((ext_vector_type(4)));
typedef float f32x4 __attribute__((ext_vector_type(4)));

__device__ __forceinline__ float clampf(float v) {
    return fminf(fmaxf(v, -60000.f), 60000.f);  // also squashes NaN
}

__device__ __forceinline__ void gl_lds16(const void* g, void* l) {
    __builtin_amdgcn_global_load_lds(
        (const __attribute__((address_space(1))) unsigned int*)g,
        (__attribute__((address_space(3))) unsigned int*)l, 16, 0, 0);
}

// ---------------- GEMM (128x128, 4 waves): C = act(A @ Bt^T + bias) ----------------
// Pure 84-VGPR form. lin3(+lin4) and non-256-multiple fallbacks.
__global__ __launch_bounds__(256) void gemm_f16(
    const f16* __restrict__ A,
    const int* __restrict__ bidx,
    const f16* __restrict__ geneT, const f16* __restrict__ disT, int rowBase,
    const f16* __restrict__ Bt, const float* __restrict__ bias,
    f16* __restrict__ C, int M, int N, int K, int relu, int CB, int RB,
    const float* __restrict__ W4, float* __restrict__ outF)
{
    alignas(16) __shared__ f16 sA[128 * 64];
    alignas(16) __shared__ f16 sB[128 * 64];
    const int t = threadIdx.x;
    const int w = t >> 6, l = t & 63;
    const int wm = w >> 1, wn = w & 1;
    const int q = l >> 4, lr = l & 15;

    int flat = blockIdx.x;
    int cb, rb;
    if ((RB & 7) == 0) {
        int x = flat & 7, idx = flat >> 3;
        int Sx = RB >> 3;
        cb = idx % CB;
        rb = x * Sx + idx / CB;
    } else {
        cb = flat % CB;
        rb = flat / CB;
    }
    const int mBase = rb * 128, nBase = cb * 128;

    const int subrow = l >> 3;   // 0..7
    const int c = l & 7;         // 16B chunk 0..7 within a 128B row
    const char* pA[4];
    const char* pD[4];
    const char* pB[4];
    const bool fused = (bidx != nullptr);
    const bool concat = (!fused && disT != nullptr);
    const bool twoSrc = fused || concat;
#pragma unroll
    for (int j = 0; j < 4; j++) {
        int seg = j * 4 + w;
        int lrow = seg * 8 + subrow;               // 0..127
        int coff = ((c ^ (lrow & 7)) << 4);        // swizzled chunk byte offset
        if (fused) {
            int rg = rowBase + mBase + lrow;       // M % 128 == 0 on this path
            int gi = bidx[2 * rg], di = bidx[2 * rg + 1];
            pA[j] = (const char*)geneT + (size_t)gi * 512 + coff;
            pD[j] = (const char*)disT + (size_t)di * 512 + coff;
        } else if (concat) {
            int arow = mBase + lrow; if (arow > M - 1) arow = M - 1;
            pA[j] = (const char*)geneT + (size_t)arow * 512 + coff;
            pD[j] = (const char*)disT + (size_t)arow * 512 + coff;
        } else {
            int arow = mBase + lrow; if (arow > M - 1) arow = M - 1;
            pA[j] = (const char*)A + (size_t)arow * K * 2 + coff;
            pD[j] = nullptr;
        }
        int brow = nBase + lrow; if (brow > N - 1) brow = N - 1;
        pB[j] = (const char*)Bt + (size_t)brow * K * 2 + coff;
    }

    f32x4 acc[4][4] = {};

    for (int k0 = 0; k0 < K; k0 += 64) {
        __syncthreads();
#pragma unroll
        for (int j = 0; j < 4; j++) {
            int seg = j * 4 + w;
            const char* srcA;
            if (twoSrc)
                srcA = (k0 < 256) ? (pA[j] + (size_t)k0 * 2) : (pD[j] + (size_t)(k0 - 256) * 2);
            else
                srcA = pA[j] + (size_t)k0 * 2;
            gl_lds16(srcA, sA + seg * 512);
            gl_lds16(pB[j] + (size_t)k0 * 2, sB + seg * 512);
        }
        __syncthreads();
        f16x8 a0[4], a1[4], b0[4], b1[4];
#pragma unroll
        for (int i = 0; i < 4; i++) {
            int r = wm * 64 + i * 16 + lr;
            int rs = r * 64;
            int x0 = (q ^ (r & 7)) << 3;
            int x1 = ((4 + q) ^ (r & 7)) << 3;
            a0[i] = *(const f16x8*)(sA + rs + x0);
            a1[i] = *(const f16x8*)(sA + rs + x1);
        }
#pragma unroll
        for (int jj = 0; jj < 4; jj++) {
            int r = wn * 64 + jj * 16 + lr;
            int rs = r * 64;
            int x0 = (q ^ (r & 7)) << 3;
            int x1 = ((4 + q) ^ (r & 7)) << 3;
            b0[jj] = *(const f16x8*)(sB + rs + x0);
            b1[jj] = *(const f16x8*)(sB + rs + x1);
        }
#pragma unroll
        for (int i = 0; i < 4; i++)
#pragma unroll
            for (int jj = 0; jj < 4; jj++) {
                acc[i][jj] = __builtin_amdgcn_mfma_f32_16x16x32_f16(a0[i], b0[jj], acc[i][jj], 0, 0, 0);
                acc[i][jj] = __builtin_amdgcn_mfma_f32_16x16x32_f16(a1[i], b1[jj], acc[i][jj], 0, 0, 0);
            }
    }

    if (W4 != nullptr) {
        // fused final linear: out[rowBase+row] += lrelu(acc + bias) @ W4 (512x2)
        float w40[4], w41[4];
#pragma unroll
        for (int j = 0; j < 4; j++) {
            int col = nBase + wn * 64 + j * 16 + lr;
            w40[j] = W4[col * 2];
            w41[j] = W4[col * 2 + 1];
        }
#pragma unroll
        for (int i = 0; i < 4; i++) {
#pragma unroll
            for (int r = 0; r < 4; r++) {
                int row = mBase + wm * 64 + i * 16 + q * 4 + r;
                float s0 = 0.f, s1 = 0.f;
#pragma unroll
                for (int j = 0; j < 4; j++) {
                    int col = nBase + wn * 64 + j * 16 + lr;
                    float v = acc[i][j][r] + bias[col];
                    v = v >= 0.f ? v : 0.01f * v;
                    v = clampf(v);
                    s0 += v * w40[j];
                    s1 += v * w41[j];
                }
#pragma unroll
                for (int off = 1; off < 16; off <<= 1) {
                    s0 += __shfl_xor(s0, off);
                    s1 += __shfl_xor(s1, off);
                }
                if (lr == 0 && row < M) {
                    atomicAdd(&outF[(size_t)(rowBase + row) * 2], s0);
                    atomicAdd(&outF[(size_t)(rowBase + row) * 2 + 1], s1);
                }
            }
        }
        return;
    }

    // ---- epilogue: per-wave LDS transpose, then coalesced f16x8 stores ----
    __syncthreads();
    f16* lt = ((w >> 1) ? sB : sA) + (w & 1) * 4096;

    float bj[4];
#pragma unroll
    for (int j = 0; j < 4; j++)
        bj[j] = bias ? bias[nBase + wn * 64 + j * 16 + lr] : 0.f;

#pragma unroll
    for (int i = 0; i < 4; i++)
#pragma unroll
        for (int j = 0; j < 4; j++) {
            int col = j * 16 + lr;
#pragma unroll
            for (int r = 0; r < 4; r++) {
                int row = i * 16 + q * 4 + r;       // 0..63 wave-local
                float v = acc[i][j][r] + bj[j];
                if (relu) v = v >= 0.f ? v : 0.01f * v;
                v = clampf(v);
                int cs = col ^ ((((row >> 2) & 3) << 4) ^ ((row & 3) << 3));
                lt[row * 64 + cs] = (f16)v;
            }
        }
    __syncthreads();

    const int rr = l >> 3;
    const int c8 = l & 7;
#pragma unroll
    for (int it = 0; it < 8; it++) {
        int row = it * 8 + rr;
        int cs = (c8 * 8) ^ ((((row >> 2) & 3) << 4) ^ ((row & 3) << 3));
        f16x8 vv = *(const f16x8*)(lt + row * 64 + cs);
        int grow = mBase + wm * 64 + row;
        if (grow < M)
            *(f16x8*)(C + (size_t)grow * N + nBase + wn * 64 + c8 * 8) = vv;
    }
}

// ---------------- R21: gemm8p — faithful 8-phase 256x256 for lin2 ----------------
// K-tile BK=64 split into 4 phases of 16 MFMA each; per phase: ds_read frags ||
// stage one half-tile (2 gl_lds16) -> s_barrier -> setprio(1) -> MFMA -> setprio(0)
// -> s_barrier. A triple-buffered (distance-2, HBM ~900cy cover), B double-buffered
// (distance-1, L2-resident weights ~200cy). Counted vmcnt: prologue vmcnt(4);
// per-tile vmcnt(4) at phase 4 (ledger: A(kt+1)4 + B(kt+1)4 + A(kt+2)4 = 12 -> 4);
// never drained to 0 mid-loop. Buffer-slot reuse separated from last read by >=2
// barriers. All barriers wave-uniform.
__global__ __launch_bounds__(512) void gemm8p(
    const f16* __restrict__ A, const f16* __restrict__ Bt,
    const float* __restrict__ bias, f16* __restrict__ C,
    int M, int N, int K, int CB, int RB)
{
    alignas(16) __shared__ f16 sm[81920];   // A: 3x16384 | B: 2x16384 (f16 units)
    f16* const smA = sm;
    f16* const smB = sm + 3 * 16384;
    const int t = threadIdx.x;
    const int w = t >> 6, l = t & 63;
    const int wm = w >> 2, wn = w & 3;      // 2 x 4 wave grid
    const int q = l >> 4, lr = l & 15;
    const int subrow = l >> 3, c = l & 7;

    int flat = blockIdx.x;
    int cb, rb;
    if ((RB & 7) == 0) {
        int x = flat & 7, idx = flat >> 3;
        int Sx = RB >> 3;
        cb = idx % CB;
        rb = x * Sx + idx / CB;
    } else {
        cb = flat % CB;
        rb = flat / CB;
    }
    const int mBase = rb * 256, nBase = cb * 256;

    const char* pA[4];
    const char* pB[4];
#pragma unroll
    for (int jj = 0; jj < 4; jj++) {
        int row = jj * 64 + w * 8 + subrow;         // 0..255 tile-local
        int coff = ((c ^ (row & 7)) << 4);          // inverse-swizzled source chunk
        int ga = mBase + row; if (ga > M - 1) ga = M - 1;
        pA[jj] = (const char*)A + (size_t)ga * K * 2 + coff;
        int gb = nBase + row; if (gb > N - 1) gb = N - 1;
        pB[jj] = (const char*)Bt + (size_t)gb * K * 2 + coff;
    }

    // stage one half (rows half*128..+127) of A or B: 2 gl_lds16 per thread
    auto stA = [&](int buf, int k0, int half) {
        f16* dst = smA + buf * 16384;
#pragma unroll
        for (int j = 0; j < 2; j++) {
            int jj = half * 2 + j;
            gl_lds16(pA[jj] + (size_t)k0 * 2, dst + (jj * 64 + w * 8) * 64);
        }
    };
    auto stB = [&](int buf, int k0, int half) {
        f16* dst = smB + buf * 16384;
#pragma unroll
        for (int j = 0; j < 2; j++) {
            int jj = half * 2 + j;
            gl_lds16(pB[jj] + (size_t)k0 * 2, dst + (jj * 64 + w * 8) * 64);
        }
    };

    f32x4 acc[8][4] = {};
    const int nkt = K >> 6;

    // prologue: T0 (A+B, 8 loads) then A(1) (4 loads); wait T0 -> vmcnt(4)
    stA(0, 0, 0); stA(0, 0, 1);
    stB(0, 0, 0); stB(0, 0, 1);
    if (nkt > 1) { stA(1, 64, 0); stA(1, 64, 1); }
    asm volatile("s_waitcnt vmcnt(4)" ::: "memory");
    __builtin_amdgcn_s_barrier();
    __builtin_amdgcn_sched_barrier(0);

    for (int kt = 0; kt < nkt; kt++) {
        const f16* bA = smA + (kt % 3) * 16384;
        const f16* bB = smB + (kt & 1) * 16384;
        const int kB1 = (kt + 1) << 6;
        const int kA2 = (kt + 2) << 6;
        f16x8 bf[4], af[4];

        // ---- phase 1: ks=0, mf 0..3; stage B(kt+1) half0 ----
#pragma unroll
        for (int nf = 0; nf < 4; nf++) {
            int rB = wn * 64 + nf * 16 + lr;
            bf[nf] = *(const f16x8*)(bB + rB * 64 + ((q ^ (rB & 7)) << 3));
        }
#pragma unroll
        for (int mf = 0; mf < 4; mf++) {
            int rA = wm * 128 + mf * 16 + lr;
            af[mf] = *(const f16x8*)(bA + rA * 64 + ((q ^ (rA & 7)) << 3));
        }
        if (kt + 1 < nkt) stB((kt + 1) & 1, kB1, 0);
        __builtin_amdgcn_sched_barrier(0);
        __builtin_amdgcn_s_barrier();
        __builtin_amdgcn_s_setprio(1);
#pragma unroll
        for (int mf = 0; mf < 4; mf++)
#pragma unroll
            for (int nf = 0; nf < 4; nf++)
                acc[mf][nf] = __builtin_amdgcn_mfma_f32_16x16x32_f16(af[mf], bf[nf], acc[mf][nf], 0, 0, 0);
        __builtin_amdgcn_s_setprio(0);
        __builtin_amdgcn_sched_barrier(0);
        __builtin_amdgcn_s_barrier();

        // ---- phase 2: ks=0, mf 4..7; stage B(kt+1) half1 ----
#pragma unroll
        for (int mf = 0; mf < 4; mf++) {
            int rA = wm * 128 + (mf + 4) * 16 + lr;
            af[mf] = *(const f16x8*)(bA + rA * 64 + ((q ^ (rA & 7)) << 3));
        }
        if (kt + 1 < nkt) stB((kt + 1) & 1, kB1, 1);
        __builtin_amdgcn_sched_barrier(0);
        __builtin_amdgcn_s_barrier();
        __builtin_amdgcn_s_setprio(1);
#pragma unroll
        for (int mf = 0; mf < 4; mf++)
#pragma unroll
            for (int nf = 0; nf < 4; nf++)
                acc[mf + 4][nf] = __builtin_amdgcn_mfma_f32_16x16x32_f16(af[mf], bf[nf], acc[mf + 4][nf], 0, 0, 0);
        __builtin_amdgcn_s_setprio(0);
        __builtin_amdgcn_sched_barrier(0);
        __builtin_amdgcn_s_barrier();

        // ---- phase 3: ks=1, mf 0..3; stage A(kt+2) half0 ----
#pragma unroll
        for (int nf = 0; nf < 4; nf++) {
            int rB = wn * 64 + nf * 16 + lr;
            bf[nf] = *(const f16x8*)(bB + rB * 64 + (((4 + q) ^ (rB & 7)) << 3));
        }
#pragma unroll
        for (int mf = 0; mf < 4; mf++) {
            int rA = wm * 128 + mf * 16 + lr;
            af[mf] = *(const f16x8*)(bA + rA * 64 + (((4 + q) ^ (rA & 7)) << 3));
        }
        if (kt + 2 < nkt) stA((kt + 2) % 3, kA2, 0);
        __builtin_amdgcn_sched_barrier(0);
        __builtin_amdgcn_s_barrier();
        __builtin_amdgcn_s_setprio(1);
#pragma unroll
        for (int mf = 0; mf < 4; mf++)
#pragma unroll
            for (int nf = 0; nf < 4; nf++)
                acc[mf][nf] = __builtin_amdgcn_mfma_f32_16x16x32_f16(af[mf], bf[nf], acc[mf][nf], 0, 0, 0);
        __builtin_amdgcn_s_setprio(0);
        __builtin_amdgcn_sched_barrier(0);
        __builtin_amdgcn_s_barrier();

        // ---- phase 4: ks=1, mf 4..7; stage A(kt+2) half1; counted vmcnt ----
#pragma unroll
        for (int mf = 0; mf < 4; mf++) {
            int rA = wm * 128 + (mf + 4) * 16 + lr;
            af[mf] = *(const f16x8*)(bA + rA * 64 + (((4 + q) ^ (rA & 7)) << 3));
        }
        if (kt + 2 < nkt) {
            stA((kt + 2) % 3, kA2, 1);
            asm volatile("s_waitcnt vmcnt(4)" ::: "memory");   // A(kt+1),B(kt+1) landed
        } else {
            asm volatile("s_waitcnt vmcnt(0)" ::: "memory");   // tail drain
        }
        __builtin_amdgcn_sched_barrier(0);
        __builtin_amdgcn_s_barrier();
        __builtin_amdgcn_s_setprio(1);
#pragma unroll
        for (int mf = 0; mf < 4; mf++)
#pragma unroll
            for (int nf = 0; nf < 4; nf++)
                acc[mf + 4][nf] = __builtin_amdgcn_mfma_f32_16x16x32_f16(af[mf], bf[nf], acc[mf + 4][nf], 0, 0, 0);
        __builtin_amdgcn_s_setprio(0);
        __builtin_amdgcn_sched_barrier(0);
        __builtin_amdgcn_s_barrier();
    }
    __builtin_amdgcn_sched_barrier(0);

    // ---- epilogue: per-wave 128x64 LDS transpose (16KB slice), f16x8 stores ----
    f16* lt = sm + w * 8192;
    float bj[4];
#pragma unroll
    for (int nf = 0; nf < 4; nf++)
        bj[nf] = bias[nBase + wn * 64 + nf * 16 + lr];

#pragma unroll
    for (int mf = 0; mf < 8; mf++)
#pragma unroll
        for (int nf = 0; nf < 4; nf++) {
            int col = nf * 16 + lr;
#pragma unroll
            for (int r = 0; r < 4; r++) {
                int row = mf * 16 + q * 4 + r;      // 0..127 wave-local
                float v = acc[mf][nf][r] + bj[nf];
                v = v >= 0.f ? v : 0.01f * v;       // lin2 always lrelu
                v = clampf(v);
                int cs = col ^ ((((row >> 2) & 3) << 4) ^ ((row & 3) << 3));
                lt[row * 64 + cs] = (f16)v;
            }
        }

    const int rr = l >> 3;
    const int c8 = l & 7;
#pragma unroll
    for (int it = 0; it < 16; it++) {
        int row = it * 8 + rr;                      // 0..127 wave-local
        int cs = (c8 * 8) ^ ((((row >> 2) & 3) << 4) ^ ((row & 3) << 3));
        f16x8 vv = *(const f16x8*)(lt + row * 64 + cs);
        int grow = mBase + wm * 128 + row;
        if (grow < M)
            *(f16x8*)(C + (size_t)grow * N + nBase + wn * 64 + c8 * 8) = vv;
    }
}

// ---------------- gemm_wide (128x512 tile, 8 waves) for lin1 gather (R20) ----------
__global__ __launch_bounds__(512) void gemm_wide(
    const int* __restrict__ bidx,
    const f16* __restrict__ geneT, const f16* __restrict__ disT, int rowBase,
    const f16* __restrict__ Bt, const float* __restrict__ bias,
    f16* __restrict__ C, int M, int N, int K, int CB, int RB)
{
    alignas(16) __shared__ f16 sm[40960];   // sA 128x64 | sB 512x64  (80 KB)
    f16* const sA = sm;
    f16* const sB = sm + 8192;
    const int t = threadIdx.x;
    const int w = t >> 6, l = t & 63;
    const int q = l >> 4, lr = l & 15;
    const int subrow = l >> 3, c = l & 7;

    int flat = blockIdx.x;
    int cb, rb;
    if ((RB & 7) == 0) {
        int x = flat & 7, idx = flat >> 3;
        int Sx = RB >> 3;
        cb = idx % CB;
        rb = x * Sx + idx / CB;
    } else {
        cb = flat % CB;
        rb = flat / CB;
    }
    const int mBase = rb * 128, nBase = cb * 512;

    const char* pA[2];
    const char* pD[2];
#pragma unroll
    for (int j = 0; j < 2; j++) {
        int row = (w * 2 + j) * 8 + subrow;
        int coff = ((c ^ (row & 7)) << 4);
        int rg = rowBase + mBase + row;            // M % 128 == 0
        int gi = bidx[2 * rg], di = bidx[2 * rg + 1];
        pA[j] = (const char*)geneT + (size_t)gi * 512 + coff;
        pD[j] = (const char*)disT + (size_t)di * 512 + coff;
    }
    const char* pB[8];
#pragma unroll
    for (int jj = 0; jj < 8; jj++) {
        int row = (jj * 8 + w) * 8 + subrow;
        int coff = ((c ^ (row & 7)) << 4);
        int brow = nBase + row; if (brow > N - 1) brow = N - 1;
        pB[jj] = (const char*)Bt + (size_t)brow * K * 2 + coff;
    }

    f32x4 acc[8][4] = {};

    for (int k0 = 0; k0 < K; k0 += 64) {
        __syncthreads();
#pragma unroll
        for (int j = 0; j < 2; j++) {
            const char* srcA = (k0 < 256) ? (pA[j] + (size_t)k0 * 2)
                                          : (pD[j] + (size_t)(k0 - 256) * 2);
            gl_lds16(srcA, sA + (w * 2 + j) * 512);
        }
#pragma unroll
        for (int jj = 0; jj < 8; jj++)
            gl_lds16(pB[jj] + (size_t)k0 * 2, sB + (jj * 8 + w) * 512);
        __syncthreads();
#pragma unroll
        for (int ks = 0; ks < 2; ks++) {
            f16x8 bf[4];
#pragma unroll
            for (int nf = 0; nf < 4; nf++) {
                int rB = w * 64 + nf * 16 + lr;
                bf[nf] = *(const f16x8*)(sB + rB * 64 + ((((ks << 2) + q) ^ (rB & 7)) << 3));
            }
#pragma unroll
            for (int mf = 0; mf < 8; mf++) {
                int rA = mf * 16 + lr;
                f16x8 af = *(const f16x8*)(sA + rA * 64 + ((((ks << 2) + q) ^ (rA & 7)) << 3));
#pragma unroll
                for (int nf = 0; nf < 4; nf++)
                    acc[mf][nf] = __builtin_amdgcn_mfma_f32_16x16x32_f16(af, bf[nf], acc[mf][nf], 0, 0, 0);
            }
        }
    }

    f16* lt = sm + w * 4096;
    float bj[4];
#pragma unroll
    for (int nf = 0; nf < 4; nf++)
        bj[nf] = bias[nBase + w * 64 + nf * 16 + lr];

    const int rr = l >> 3;
    const int c8 = l & 7;
#pragma unroll
    for (int half = 0; half < 2; half++) {
        __syncthreads();
#pragma unroll
        for (int mh = 0; mh < 4; mh++) {
            int mf = half * 4 + mh;
#pragma unroll
            for (int nf = 0; nf < 4; nf++) {
                int col = nf * 16 + lr;
#pragma unroll
                for (int r = 0; r < 4; r++) {
                    int row = mh * 16 + q * 4 + r;
                    float v = acc[mf][nf][r] + bj[nf];
                    v = v >= 0.f ? v : 0.01f * v;
                    v = clampf(v);
                    int cs = col ^ ((((row >> 2) & 3) << 4) ^ ((row & 3) << 3));
                    lt[row * 64 + cs] = (f16)v;
                }
            }
        }
        __syncthreads();
#pragma unroll
        for (int it = 0; it < 8; it++) {
            int row = it * 8 + rr;
            int cs = (c8 * 8) ^ ((((row >> 2) & 3) << 4) ^ ((row & 3) << 3));
            f16x8 vv = *(const f16x8*)(lt + row * 64 + cs);
            int grow = mBase + half * 64 + row;
            if (grow < M)
                *(f16x8*)(C + (size_t)grow * N + nBase + w * 64 + c8 * 8) = vv;
        }
    }
}

// ---------------- merged tower GEMM: gene blocks then disease blocks ----------------
__global__ __launch_bounds__(256) void gemm_tower2(
    const f16* __restrict__ Xg, const f16* __restrict__ XAg,
    const f16* __restrict__ Btg, const float* __restrict__ biasg,
    f16* __restrict__ Cg, int Mg, int RBg, float* __restrict__ statsg,
    const f16* __restrict__ Xd, const f16* __restrict__ XAd,
    const f16* __restrict__ Btd, const float* __restrict__ biasd,
    f16* __restrict__ Cd, int Md, int RBd, float* __restrict__ statsd)
{
    alignas(16) __shared__ f16 sA[128 * 64];
    alignas(16) __shared__ f16 sB[128 * 64];
    const int t = threadIdx.x;
    const int w = t >> 6, l = t & 63;
    const int wm = w >> 1, wn = w & 1;
    const int q = l >> 4, lr = l & 15;

    int flat = blockIdx.x;
    const int geneBlocks = 2 * RBg;
    const f16* X;  const f16* XA;  const f16* Bt;  const float* bias;
    f16* C;  int M, RB;  float* stats;
    if (flat < geneBlocks) {
        X = Xg; XA = XAg; Bt = Btg; bias = biasg; C = Cg; M = Mg; RB = RBg; stats = statsg;
    } else {
        flat -= geneBlocks;
        X = Xd; XA = XAd; Bt = Btd; bias = biasd; C = Cd; M = Md; RB = RBd; stats = statsd;
    }

    int cb, rb;
    if ((RB & 7) == 0) {
        int x = flat & 7, idx = flat >> 3;
        int Sx = RB >> 3;
        cb = idx % 2;
        rb = x * Sx + idx / 2;
    } else {
        cb = flat % 2;
        rb = flat / 2;
    }
    const int mBase = rb * 128, nBase = cb * 128;

    const int subrow = l >> 3;
    const int c = l & 7;
    const char* pA[4];
    const char* pD[4];
    const char* pB[4];
#pragma unroll
    for (int j = 0; j < 4; j++) {
        int seg = j * 4 + w;
        int lrow = seg * 8 + subrow;
        int coff = ((c ^ (lrow & 7)) << 4);
        int arow = mBase + lrow; if (arow > M - 1) arow = M - 1;
        pA[j] = (const char*)X + (size_t)arow * 512 + coff;
        pD[j] = (const char*)XA + (size_t)arow * 512 + coff;
        int brow = nBase + lrow; if (brow > 255) brow = 255;
        pB[j] = (const char*)Bt + (size_t)brow * 1024 + coff;
    }

    f32x4 acc[4][4] = {};

    for (int k0 = 0; k0 < 512; k0 += 64) {
        __syncthreads();
#pragma unroll
        for (int j = 0; j < 4; j++) {
            int seg = j * 4 + w;
            const char* srcA = (k0 < 256) ? (pA[j] + (size_t)k0 * 2)
                                          : (pD[j] + (size_t)(k0 - 256) * 2);
            gl_lds16(srcA, sA + seg * 512);
            gl_lds16(pB[j] + (size_t)k0 * 2, sB + seg * 512);
        }
        __syncthreads();
        f16x8 a0[4], a1[4], b0[4], b1[4];
#pragma unroll
        for (int i = 0; i < 4; i++) {
            int r = wm * 64 + i * 16 + lr;
            int rs = r * 64;
            int x0 = (q ^ (r & 7)) << 3;
            int x1 = ((4 + q) ^ (r & 7)) << 3;
            a0[i] = *(const f16x8*)(sA + rs + x0);
            a1[i] = *(const f16x8*)(sA + rs + x1);
        }
#pragma unroll
        for (int jj = 0; jj < 4; jj++) {
            int r = wn * 64 + jj * 16 + lr;
            int rs = r * 64;
            int x0 = (q ^ (r & 7)) << 3;
            int x1 = ((4 + q) ^ (r & 7)) << 3;
            b0[jj] = *(const f16x8*)(sB + rs + x0);
            b1[jj] = *(const f16x8*)(sB + rs + x1);
        }
#pragma unroll
        for (int i = 0; i < 4; i++)
#pragma unroll
            for (int jj = 0; jj < 4; jj++) {
                acc[i][jj] = __builtin_amdgcn_mfma_f32_16x16x32_f16(a0[i], b0[jj], acc[i][jj], 0, 0, 0);
                acc[i][jj] = __builtin_amdgcn_mfma_f32_16x16x32_f16(a1[i], b1[jj], acc[i][jj], 0, 0, 0);
            }
    }

    __syncthreads();
    f16* lt = ((w >> 1) ? sB : sA) + (w & 1) * 4096;

    float bj[4];
#pragma unroll
    for (int j = 0; j < 4; j++)
        bj[j] = bias[nBase + wn * 64 + j * 16 + lr];

    float sj[4] = {0.f, 0.f, 0.f, 0.f}, s2j[4] = {0.f, 0.f, 0.f, 0.f};
#pragma unroll
    for (int i = 0; i < 4; i++)
#pragma unroll
        for (int j = 0; j < 4; j++) {
            int col = j * 16 + lr;
#pragma unroll
            for (int r = 0; r < 4; r++) {
                int row = i * 16 + q * 4 + r;
                float v = acc[i][j][r] + bj[j];
                v = v >= 0.f ? v : 0.01f * v;
                v = clampf(v);
                if ((mBase + wm * 64 + row) < M) { sj[j] += v; s2j[j] += v * v; }
                int cs = col ^ ((((row >> 2) & 3) << 4) ^ ((row & 3) << 3));
                lt[row * 64 + cs] = (f16)v;
            }
        }

#pragma unroll
    for (int j = 0; j < 4; j++) {
        float s = sj[j], s2 = s2j[j];
        s += __shfl_xor(s, 16); s2 += __shfl_xor(s2, 16);
        s += __shfl_xor(s, 32); s2 += __shfl_xor(s2, 32);
        if (q == 0) {
            int col = nBase + wn * 64 + j * 16 + lr;
            atomicAdd(&stats[col], s);
            atomicAdd(&stats[256 + col], s2);
        }
    }
    __syncthreads();

    const int rr = l >> 3;
    const int c8 = l & 7;
#pragma unroll
    for (int it = 0; it < 8; it++) {
        int row = it * 8 + rr;
        int cs = (c8 * 8) ^ ((((row >> 2) & 3) << 4) ^ ((row & 3) << 3));
        f16x8 vv = *(const f16x8*)(lt + row * 64 + cs);
        int grow = mBase + wm * 64 + row;
        if (grow < M)
            *(f16x8*)(C + (size_t)grow * 256 + nBase + wn * 64 + c8 * 8) = vv;
    }
}

// ---------------- merged small kernels ----------------
__global__ void cvt2(const float* __restrict__ gx, const float* __restrict__ dx,
                     f16* __restrict__ og, f16* __restrict__ od) {
    size_t i = ((size_t)blockIdx.x * 256 + threadIdx.x) * 8;
    const size_t ng = (size_t)N_G * 256;
    const float* in; f16* out;
    if (i < ng) { in = gx + i; out = og + i; }
    else {
        size_t j = i - ng;
        if (j >= (size_t)N_D * 256) return;
        in = dx + j; out = od + j;
    }
    f32x4 a = *(const f32x4*)in;
    f32x4 b = *(const f32x4*)(in + 4);
    f16x8 o;
    o[0] = (f16)clampf(a.x); o[1] = (f16)clampf(a.y);
    o[2] = (f16)clampf(a.z); o[3] = (f16)clampf(a.w);
    o[4] = (f16)clampf(b.x); o[5] = (f16)clampf(b.y);
    o[6] = (f16)clampf(b.z); o[7] = (f16)clampf(b.w);
    *(f16x8*)out = o;
}

__global__ void init_out(const float* __restrict__ b4, float* __restrict__ out, int n) {
    int i = blockIdx.x * 256 + threadIdx.x;
    if (i < n) out[i] = b4[i & 1];
}

__global__ void count_deg2(const int* __restrict__ gei, const int* __restrict__ dei,
                           int* __restrict__ cntg, int* __restrict__ cntd) {
    int e = blockIdx.x * 256 + threadIdx.x;
    if (e < E_G) atomicAdd(&cntg[gei[E_G + e]], 1);
    else if (e < E_G + E_D) atomicAdd(&cntd[dei[E_D + (e - E_G)]], 1);
}

__global__ void scan_deg2(const int* __restrict__ cntg, int* __restrict__ rpg,
                          const int* __restrict__ cntd, int* __restrict__ rpd) {
    __shared__ int part[1024];
    const int t = threadIdx.x;
    const int* deg = blockIdx.x ? cntd : cntg;
    int* rowptr = blockIdx.x ? rpd : rpg;
    const int Nn = blockIdx.x ? N_D : N_G;
    const int C = (Nn + 1023) >> 10;
    const int base = t * C;
    int s = 0;
    for (int i = 0; i < C; i++) { int idx = base + i; if (idx < Nn) s += deg[idx]; }
    part[t] = s;
    __syncthreads();
    for (int off = 1; off < 1024; off <<= 1) {
        int v = (t >= off) ? part[t - off] : 0;
        __syncthreads();
        part[t] += v;
        __syncthreads();
    }
    int pre = (t == 0) ? 0 : part[t - 1];
    for (int i = 0; i < C; i++) {
        int idx = base + i;
        if (idx < Nn) { rowptr[idx] = pre; pre += deg[idx]; }
    }
    if (t == 1023) rowptr[Nn] = part[1023];
}

__global__ void fill_csr2(const int* __restrict__ gei, const int* __restrict__ dei,
                          const int* __restrict__ rpg, const int* __restrict__ rpd,
                          int* __restrict__ curg, int* __restrict__ curd,
                          int* __restrict__ csrg, int* __restrict__ csrd) {
    int e = blockIdx.x * 256 + threadIdx.x;
    if (e < E_G) {
        int d = gei[E_G + e];
        int p = rpg[d] + atomicAdd(&curg[d], 1);
        csrg[p] = gei[e];
    } else if (e < E_G + E_D) {
        int e2 = e - E_G;
        int d = dei[E_D + e2];
        int p = rpd[d] + atomicAdd(&curd[d], 1);
        csrd[p] = dei[e2];
    }
}

__global__ void agg_x2(const int* __restrict__ rpg, const int* __restrict__ csrg,
                       const f16* __restrict__ Xg, f16* __restrict__ XAg,
                       const int* __restrict__ rpd, const int* __restrict__ csrd,
                       const f16* __restrict__ Xd, f16* __restrict__ XAd) {
    int gid = blockIdx.x * 256 + threadIdx.x;
    int node = gid >> 6, l = gid & 63;
    const int* rowptr; const int* csr; const f16* X; f16* XA;
    if (node < N_G) { rowptr = rpg; csr = csrg; X = Xg; XA = XAg; }
    else {
        node -= N_G;
        if (node >= N_D) return;
        rowptr = rpd; csr = csrd; X = Xd; XA = XAd;
    }
    int beg = rowptr[node], end = rowptr[node + 1];
    float s0 = 0.f, s1 = 0.f, s2 = 0.f, s3 = 0.f;
    for (int e = beg; e < end; e++) {
        int src = csr[e];
        f16x4 xv = *(const f16x4*)(X + (size_t)src * 256 + l * 4);
        s0 += (float)xv.x; s1 += (float)xv.y; s2 += (float)xv.z; s3 += (float)xv.w;
    }
    f16x4 o;
    o.x = (f16)clampf(s0); o.y = (f16)clampf(s1);
    o.z = (f16)clampf(s2); o.w = (f16)clampf(s3);
    *(f16x4*)(XA + (size_t)node * 256 + l * 4) = o;
}

__global__ void bn_apply2(f16* __restrict__ yg, f16* __restrict__ yd,
                          const float* __restrict__ stg, const float* __restrict__ std_,
                          const float* __restrict__ gg, const float* __restrict__ bg,
                          const float* __restrict__ gd, const float* __restrict__ bd,
                          float invNg, float invNd, float wv,
                          f16* __restrict__ accg, f16* __restrict__ accd, int initAcc) {
    size_t i = ((size_t)blockIdx.x * 256 + threadIdx.x) * 8;
    const size_t ng = (size_t)N_G * 256;
    f16* y; f16* acc; const float* stats; const float* g; const float* b; float invN;
    if (i < ng) { y = yg + i; acc = accg + i; stats = stg; g = gg; b = bg; invN = invNg; }
    else {
        size_t j = i - ng;
        if (j >= (size_t)N_D * 256) return;
        y = yd + j; acc = accd + j; stats = std_; g = gd; b = bd; invN = invNd;
    }
    int colb = (int)(i & 255);
    f16x8 yv = *(const f16x8*)y;
    f16x8 av = {};
    if (!initAcc) av = *(const f16x8*)acc;
    f16x8 yo, ao;
#pragma unroll
    for (int j = 0; j < 8; j++) {
        int col = colb + j;
        float m = stats[col] * invN;
        float var = stats[256 + col] * invN - m * m;
        if (var < 0.f) var = 0.f;
        float rs = 1.0f / sqrtf(var + 1e-5f);
        float v = ((float)yv[j] - m) * rs * g[col] + b[col];
        v = clampf(v);
        yo[j] = (f16)v;
        float p = initAcc ? 0.f : (float)av[j];
        ao[j] = (f16)clampf(p + wv * v);
    }
    *(f16x8*)y = yo;
    *(f16x8*)acc = ao;
}

__global__ void transpose_tile(const float* __restrict__ W, f16* __restrict__ WT,
                               int K, int N, int dstRowOff, int dstColOff, int LK) {
    __shared__ float tile[32][33];
    int n0 = blockIdx.x * 32, k0 = blockIdx.y * 32;
    int tx = threadIdx.x, ty = threadIdx.y;
    for (int yy = ty; yy < 32; yy += 8) {
        int k = k0 + yy, n = n0 + tx;
        tile[yy][tx] = (k < K && n < N) ? W[(size_t)k * N + n] : 0.f;
    }
    __syncthreads();
    for (int yy = ty; yy < 32; yy += 8) {
        int n = n0 + yy, k = k0 + tx;
        if (n < N && k < K)
            WT[(size_t)(dstRowOff + n) * LK + dstColOff + k] = (f16)clampf(tile[tx][yy]);
    }
}

struct WPtrs { const float* p[12]; };
__global__ void transpose12(WPtrs wp, f16* __restrict__ WT) {
    __shared__ float tile[32][33];
    const int z = blockIdx.z;
    const float* W = wp.p[z];
    const int s = z >> 1;
    const int colOff = (z & 1) * 256;
    f16* dst = WT + (size_t)s * 131072;
    int n0 = blockIdx.x * 32, k0 = blockIdx.y * 32;
    int tx = threadIdx.x, ty = threadIdx.y;
    for (int yy = ty; yy < 32; yy += 8)
        tile[yy][tx] = W[(size_t)(k0 + yy) * 256 + n0 + tx];
    __syncthreads();
    for (int yy = ty; yy < 32; yy += 8)
        dst[(size_t)(n0 + yy) * 512 + colOff + k0 + tx] = (f16)clampf(tile[tx][yy]);
}

extern "C" void kernel_launch(void* const* d_in, const int* in_sizes, int n_in,
                              void* d_out, int out_size, void* d_ws, size_t ws_size,
                              hipStream_t stream) {
    char* ws = (char*)d_ws;
    size_t off = 0;
    auto alloc = [&](size_t bytes) -> void* {
        void* p = ws + off;
        off += (bytes + 255) & ~(size_t)255;
        return p;
    };

    f16* gene_out = (f16*)alloc((size_t)N_G * 256 * 2);
    f16* dis_out  = (f16*)alloc((size_t)N_D * 256 * 2);
    f16* W1T = (f16*)alloc((size_t)2048 * 512 * 2);
    f16* W2T = (f16*)alloc((size_t)1024 * 2048 * 2);
    f16* W3T = (f16*)alloc((size_t)512 * 1024 * 2);
    f16* WcatT = (f16*)alloc((size_t)6 * 256 * 512 * 2);
    int* csr_g = (int*)alloc((size_t)E_G * 4);
    int* csr_d = (int*)alloc((size_t)E_D * 4);
    int* rp_g = (int*)alloc((size_t)(N_G + 1) * 4);
    int* rp_d = (int*)alloc((size_t)(N_D + 1) * 4);
    int* cnt = (int*)alloc((size_t)(N_G + N_D) * 4);
    int* cnt_g = cnt;
    int* cnt_d = cnt + N_G;
    float* statsAll = (float*)alloc(6 * 512 * 4);

    char* scratch = ws + off;
    size_t avail = (ws_size > off) ? (ws_size - off) : 0;

    const size_t NSG = (size_t)N_G * 256;
    const size_t NSD = (size_t)N_D * 256;
    f16* gX = (f16*)scratch;
    f16* gY = gX + NSG;
    f16* gXA = gY + NSG;
    f16* dX = gXA + NSG;
    f16* dY = dX + NSD;
    f16* dXA = dY + NSD;

    int R = BATCH;
    while ((size_t)R * 6144 > avail && R > 256) R >>= 1;
    int chunks = BATCH / R;
    f16* h1 = (f16*)scratch;
    f16* h2 = h1 + (size_t)R * 2048;

    const float* gene_x = (const float*)d_in[0];
    const float* disease_x = (const float*)d_in[1];
    const int* g_ei = (const int*)d_in[2];
    const int* d_ei = (const int*)d_in[3];
    const int* bidx = (const int*)d_in[4];
    float* out = (float*)d_out;

    const float wl[3] = {0.7f, 0.2f, 0.1f};

    // ---- tower setup (merged) ----
    hipMemsetAsync(statsAll, 0, 6 * 512 * 4, stream);
    hipMemsetAsync(cnt, 0, (size_t)(N_G + N_D) * 4, stream);
    {
        size_t tot8 = ((NSG + NSD) / 8 + 255) / 256;
        cvt2<<<(int)tot8, 256, 0, stream>>>(gene_x, disease_x, gX, dX);
    }
    count_deg2<<<(E_G + E_D + 255) / 256, 256, 0, stream>>>(g_ei, d_ei, cnt_g, cnt_d);
    scan_deg2<<<2, 1024, 0, stream>>>(cnt_g, rp_g, cnt_d, rp_d);
    hipMemsetAsync(cnt, 0, (size_t)(N_G + N_D) * 4, stream);
    fill_csr2<<<(E_G + E_D + 255) / 256, 256, 0, stream>>>(g_ei, d_ei, rp_g, rp_d,
                                                           cnt_g, cnt_d, csr_g, csr_d);
    {
        WPtrs wp;
        for (int l = 0; l < 3; l++) {
            wp.p[l * 2 + 0] = (const float*)d_in[5 + l * 5 + 2];
            wp.p[l * 2 + 1] = (const float*)d_in[5 + l * 5 + 0];
            wp.p[6 + l * 2 + 0] = (const float*)d_in[20 + l * 5 + 2];
            wp.p[6 + l * 2 + 1] = (const float*)d_in[20 + l * 5 + 0];
        }
        transpose12<<<dim3(8, 8, 12), dim3(32, 8), 0, stream>>>(wp, WcatT);
    }

    // ---- tower layers (merged) ----
    const int RBg = ((N_G + 127) / 128 + 7) & ~7;
    const int RBd = ((N_D + 127) / 128 + 7) & ~7;
    f16* gIn = gX; f16* gOut = gY;
    f16* dIn = dX; f16* dOut = dY;
    int aggBlocks = ((N_G + N_D) * 64 + 255) / 256;
    int bnBlocks = (int)(((NSG + NSD) / 8 + 255) / 256);
    for (int l = 0; l < 3; l++) {
        const float* br_g = (const float*)d_in[5 + l * 5 + 1];
        const float* bg_g = (const float*)d_in[5 + l * 5 + 3];
        const float* bb_g = (const float*)d_in[5 + l * 5 + 4];
        const float* br_d = (const float*)d_in[20 + l * 5 + 1];
        const float* bg_d = (const float*)d_in[20 + l * 5 + 3];
        const float* bb_d = (const float*)d_in[20 + l * 5 + 4];
        agg_x2<<<aggBlocks, 256, 0, stream>>>(rp_g, csr_g, gIn, gXA,
                                              rp_d, csr_d, dIn, dXA);
        gemm_tower2<<<2 * RBg + 2 * RBd, 256, 0, stream>>>(
            gIn, gXA, WcatT + (size_t)l * 131072, br_g, gOut, N_G, RBg, statsAll + l * 512,
            dIn, dXA, WcatT + (size_t)(3 + l) * 131072, br_d, dOut, N_D, RBd,
            statsAll + (3 + l) * 512);
        bn_apply2<<<bnBlocks, 256, 0, stream>>>(gOut, dOut,
                                                statsAll + l * 512, statsAll + (3 + l) * 512,
                                                bg_g, bb_g, bg_d, bb_d,
                                                1.0f / N_G, 1.0f / N_D, wl[l],
                                                gene_out, dis_out, l == 0);
        f16* tmp = gIn; gIn = gOut; gOut = tmp;
        tmp = dIn; dIn = dOut; dOut = tmp;
    }

    // ---- head ----
    const float* lin1_W = (const float*)d_in[35];
    const float* lin1_b = (const float*)d_in[36];
    const float* lin2_W = (const float*)d_in[37];
    const float* lin2_b = (const float*)d_in[38];
    const float* lin3_W = (const float*)d_in[39];
    const float* lin3_b = (const float*)d_in[40];
    const float* lin4_W = (const float*)d_in[41];
    const float* lin4_b = (const float*)d_in[42];

    transpose_tile<<<dim3(64, 16), dim3(32, 8), 0, stream>>>(lin1_W, W1T, 512, 2048, 0, 0, 512);
    transpose_tile<<<dim3(32, 64), dim3(32, 8), 0, stream>>>(lin2_W, W2T, 2048, 1024, 0, 0, 2048);
    transpose_tile<<<dim3(16, 32), dim3(32, 8), 0, stream>>>(lin3_W, W3T, 1024, 512, 0, 0, 1024);
    init_out<<<(BATCH * 2 + 255) / 256, 256, 0, stream>>>(lin4_b, out, BATCH * 2);

    // head: lin1 -> gemm_wide, lin2 -> gemm8p (R21, 8-phase), lin3 -> gemm_f16
    for (int c = 0; c < chunks; c++) {
        int rb = c * R;
        int RB = R / 128;
        if ((R & 127) == 0) {
            gemm_wide<<<4 * RB, 512, 0, stream>>>(bidx, gene_out, dis_out, rb,
                                                  W1T, lin1_b, h1, R, 2048, 512, 4, RB);
        } else {
            gemm_f16<<<16 * RB, 256, 0, stream>>>(nullptr, bidx, gene_out, dis_out, rb,
                                                  W1T, lin1_b, h1, R, 2048, 512, 1, 16, RB,
                                                  nullptr, nullptr);
        }
        if ((R & 255) == 0) {
            int RB2 = R / 256;
            gemm8p<<<4 * RB2, 512, 0, stream>>>(h1, W2T, lin2_b, h2, R, 1024, 2048, 4, RB2);
        } else {
            gemm_f16<<<8 * RB, 256, 0, stream>>>(h1, nullptr, nullptr, nullptr, 0,
                                                 W2T, lin2_b, h2, R, 1024, 2048, 1, 8, RB,
                                                 nullptr, nullptr);
        }
        gemm_f16<<<4 * RB, 256, 0, stream>>>(h2, nullptr, nullptr, nullptr, rb,
                                             W3T, lin3_b, nullptr, R, 512, 1024, 1, 4, RB,
                                             lin4_W, out);
    }
}